// Round 1
// baseline (83.813 us; speedup 1.0000x reference)
//
#include <hip/hip_runtime.h>

// ADC activation: out = 0.05 * searchsorted(adc_char, clamp(x,0,7.9375), 'right') / 16
// x: (128,128,56,56) fp32 = 51,380,224 elems; adc_char: 127 sorted fp32 thresholds.
// Memory-bound: 411 MB total traffic -> ~65us at 6.3 TB/s.

#define N_LEVELS 127
#define CLAMP_MAX 7.9375f
#define OUT_SCALE 0.003125f  // 0.05 / 2^4 (exact: fl(0.05f)/16 is an exponent shift)

// Bank-replicated LUT: copy c (c = lane&31) stores threshold j at lut[j*32 + c].
// Lane with copy c always reads bank c -> no bank conflicts regardless of the
// divergent binary-search path (lanes l and l+32 share a copy: free 2-way).
__device__ __forceinline__ float adc_one(const float* __restrict__ my, float x) {
    float a = fminf(fmaxf(x, 0.0f), CLAMP_MAX);
    int cnt = 0;  // count of thresholds <= a  (searchsorted side='right'), 0..127
    // n = 127 = 2^7 - 1: perfectly balanced predicated binary search, 7 LDS reads.
    if (my[(cnt + 63) << 5] <= a) cnt += 64;
    if (my[(cnt + 31) << 5] <= a) cnt += 32;
    if (my[(cnt + 15) << 5] <= a) cnt += 16;
    if (my[(cnt +  7) << 5] <= a) cnt += 8;
    if (my[(cnt +  3) << 5] <= a) cnt += 4;
    if (my[(cnt +  1) << 5] <= a) cnt += 2;
    if (my[(cnt +  0) << 5] <= a) cnt += 1;
    return OUT_SCALE * (float)cnt;
}

__global__ __launch_bounds__(256) void ADCActivation_55465207660703_kernel(
        const float* __restrict__ x,
        const float* __restrict__ adc_char,
        float* __restrict__ out,
        int n4, int rem) {
    __shared__ float lut[N_LEVELS * 32];  // 16256 B

    const int tid = threadIdx.x;
    // Fill the 32 transposed copies: lut[j*32 + c] = adc_char[j].
    // 4064 entries / 256 threads = 16 iters; adc_char is L2-resident after block 0.
    for (int i = tid; i < N_LEVELS * 32; i += 256) {
        lut[i] = adc_char[i >> 5];
    }
    __syncthreads();

    const float* my = lut + (tid & 31);

    const float4* __restrict__ x4 = (const float4*)x;
    float4* __restrict__ o4 = (float4*)out;

    int idx = blockIdx.x * 256 + tid;
    const int stride = gridDim.x * 256;
    for (int i = idx; i < n4; i += stride) {
        float4 v = x4[i];
        float4 r;
        r.x = adc_one(my, v.x);
        r.y = adc_one(my, v.y);
        r.z = adc_one(my, v.z);
        r.w = adc_one(my, v.w);
        o4[i] = r;
    }

    // Tail (n % 4 != 0) — not hit for this problem (n = 51,380,224) but safe.
    if (blockIdx.x == 0 && tid < rem) {
        int e = n4 * 4 + tid;
        out[e] = adc_one(my, x[e]);
    }
}

extern "C" void kernel_launch(void* const* d_in, const int* in_sizes, int n_in,
                              void* d_out, int out_size, void* d_ws, size_t ws_size,
                              hipStream_t stream) {
    const float* x        = (const float*)d_in[0];
    const float* adc_char = (const float*)d_in[1];
    float* out            = (float*)d_out;

    const int n   = in_sizes[0];
    const int n4  = n >> 2;
    const int rem = n & 3;

    // Grid-stride: ~24 float4/thread at 2048 blocks; enough waves to hide HBM latency.
    int blocks = (n4 + 255) / 256;
    if (blocks > 2048) blocks = 2048;
    if (blocks < 1) blocks = 1;

    ADCActivation_55465207660703_kernel<<<blocks, 256, 0, stream>>>(x, adc_char, out, n4, rem);
}